// Round 8
// baseline (38.953 us; speedup 1.0000x reference)
//
#include <hip/hip_runtime.h>
#include <hip/hip_bf16.h>

#define BB   32
#define SS   1024
#define RR   1024
#define HID  512
#define OUTD 1024

typedef float v4f __attribute__((ext_vector_type(4)));

// Layer 1: 256-thread blocks, 4 waves. Wave w owns 4 j-rows x 2 batches.
// 16-lane group g owns row j; W1 row read once, reused for both batches.
// Block = (j-group of 16, b-pair). Grid = 32 * 16 = 512 blocks.
__global__ __launch_bounds__(256) void layer1_kernel(
    const float* __restrict__ rep, const float* __restrict__ W1,
    const float* __restrict__ b1, float* __restrict__ h) {
  const int tid  = threadIdx.x;
  const int wave = tid >> 6;
  const int lane = tid & 63;
  const int g    = lane >> 4;
  const int l16  = lane & 15;
  const int jg   = blockIdx.x >> 4;            // 0..31  (16 j's each)
  const int b0   = (blockIdx.x & 15) << 1;     // 0,2,..,30
  const int j    = (jg << 4) + (wave << 2) + g;

  const float4* w4 = reinterpret_cast<const float4*>(W1 + (size_t)j * RR);
  const float4* r0 = reinterpret_cast<const float4*>(rep + (size_t)b0 * RR);
  const float4* r1 = reinterpret_cast<const float4*>(rep + (size_t)(b0 + 1) * RR);
  float a0 = 0.f, a1 = 0.f;
#pragma unroll
  for (int t = 0; t < 16; ++t) {               // 256 float4 / 16 lanes
    const float4 w = w4[l16 + 16 * t];
    const float4 x = r0[l16 + 16 * t];
    const float4 y = r1[l16 + 16 * t];
    a0 += w.x * x.x + w.y * x.y + w.z * x.z + w.w * x.w;
    a1 += w.x * y.x + w.y * y.y + w.z * y.z + w.w * y.w;
  }
#pragma unroll
  for (int m = 1; m <= 8; m <<= 1) {
    a0 += __shfl_xor(a0, m);
    a1 += __shfl_xor(a1, m);
  }
  if (l16 == 0) {
    const float bb = b1[j];
    h[(size_t)b0 * HID + j]       = fmaxf(a0 + bb, 0.f);
    h[(size_t)(b0 + 1) * HID + j] = fmaxf(a1 + bb, 0.f);
  }
}

// Layer 2: 256-thread blocks, wave owns 4 k-rows x 2 batches (512-dot).
// Block = (k-group of 16, b-pair). Grid = 64 * 16 = 1024 blocks.
__global__ __launch_bounds__(256) void layer2_kernel(
    const float* __restrict__ h, const float* __restrict__ W2,
    const float* __restrict__ b2, float* __restrict__ out) {
  const int tid  = threadIdx.x;
  const int wave = tid >> 6;
  const int lane = tid & 63;
  const int g    = lane >> 4;
  const int l16  = lane & 15;
  const int kg   = blockIdx.x >> 4;            // 0..63
  const int b0   = (blockIdx.x & 15) << 1;
  const int k    = (kg << 4) + (wave << 2) + g;

  const float4* w4 = reinterpret_cast<const float4*>(W2 + (size_t)k * HID);
  const float4* h0 = reinterpret_cast<const float4*>(h + (size_t)b0 * HID);
  const float4* h1 = reinterpret_cast<const float4*>(h + (size_t)(b0 + 1) * HID);
  float a0 = 0.f, a1 = 0.f;
#pragma unroll
  for (int t = 0; t < 8; ++t) {                // 128 float4 / 16 lanes
    const float4 w = w4[l16 + 16 * t];
    const float4 x = h0[l16 + 16 * t];
    const float4 y = h1[l16 + 16 * t];
    a0 += w.x * x.x + w.y * x.y + w.z * x.z + w.w * x.w;
    a1 += w.x * y.x + w.y * y.y + w.z * y.z + w.w * y.w;
  }
#pragma unroll
  for (int m = 1; m <= 8; m <<= 1) {
    a0 += __shfl_xor(a0, m);
    a1 += __shfl_xor(a1, m);
  }
  if (l16 == 0) {
    const float bb = b2[k];
    out[(size_t)b0 * SS * OUTD + k]       = a0 + bb;
    out[(size_t)(b0 + 1) * SS * OUTD + k] = a1 + bb;
  }
}

// Broadcast: block = (b, s-chunk of 8 rows). Grid = 32*128 = 4096 blocks.
// Each thread reads one float4 of out[b,0,:] (L2-hot) and streams it to 8
// rows with non-temporal stores (write-once data; don't pollute L2).
__global__ __launch_bounds__(256) void bcast_kernel(float* __restrict__ out) {
  const int b  = blockIdx.x >> 7;              // 0..31
  const int sc = blockIdx.x & 127;             // 0..127
  v4f* __restrict__ base =
      reinterpret_cast<v4f*>(out) + (size_t)b * SS * (OUTD / 4);
  const v4f v = base[threadIdx.x];             // source row s=0
  const int s0 = sc << 3;
#pragma unroll
  for (int i = 0; i < 8; ++i) {
    const int s = s0 + i;
    if (s != 0)
      __builtin_nontemporal_store(v, &base[(size_t)s * (OUTD / 4) + threadIdx.x]);
  }
}

extern "C" void kernel_launch(void* const* d_in, const int* in_sizes, int n_in,
                              void* d_out, int out_size, void* d_ws, size_t ws_size,
                              hipStream_t stream) {
  const float* rep = (const float*)d_in[0];
  // d_in[1] = size_matrix: only its shape matters (ones_like) -> unused
  const float* W1 = (const float*)d_in[2];
  const float* b1 = (const float*)d_in[3];
  const float* W2 = (const float*)d_in[4];
  const float* b2 = (const float*)d_in[5];
  float* out = (float*)d_out;
  float* h   = (float*)d_ws;                   // 32*512 floats = 64 KB

  layer1_kernel<<<512, 256, 0, stream>>>(rep, W1, b1, h);
  layer2_kernel<<<1024, 256, 0, stream>>>(h, W2, b2, out);
  bcast_kernel<<<BB * 128, 256, 0, stream>>>(out);
}

// Round 9
// 35.544 us; speedup vs baseline: 1.0959x; 1.0959x over previous
//
#include <hip/hip_runtime.h>
#include <hip/hip_bf16.h>

#define BB   32
#define SS   1024
#define RR   1024
#define HID  512
#define OUTD 1024

// Layer 1: one wave per (4-j tile, 4-batch tile). 16-lane group g owns row
// j; W1 row is read ONCE per wave and reused across 4 batches (8 total
// W1 passes vs 32 naive). 5 independent load streams per iteration.
// Grid: 128 j-quads * 8 b-quads = 1024 one-wave blocks.
__global__ __launch_bounds__(64) void layer1_kernel(
    const float* __restrict__ rep, const float* __restrict__ W1,
    const float* __restrict__ b1, float* __restrict__ h) {
  const int lane = threadIdx.x;
  const int g    = lane >> 4;
  const int l16  = lane & 15;
  const int jq   = blockIdx.x >> 3;        // 0..127
  const int b0   = (blockIdx.x & 7) << 2;  // 0,4,..,28
  const int j    = (jq << 2) + g;

  const float4* w4 = reinterpret_cast<const float4*>(W1 + (size_t)j * RR);
  const float4* r0 = reinterpret_cast<const float4*>(rep + (size_t)b0 * RR);
  const float4* r1 = reinterpret_cast<const float4*>(rep + (size_t)(b0 + 1) * RR);
  const float4* r2 = reinterpret_cast<const float4*>(rep + (size_t)(b0 + 2) * RR);
  const float4* r3 = reinterpret_cast<const float4*>(rep + (size_t)(b0 + 3) * RR);
  float a0 = 0.f, a1 = 0.f, a2 = 0.f, a3 = 0.f;
#pragma unroll
  for (int t = 0; t < 16; ++t) {           // 256 float4 / 16 lanes
    const int idx = l16 + 16 * t;
    const float4 w = w4[idx];
    const float4 x0 = r0[idx];
    const float4 x1 = r1[idx];
    const float4 x2 = r2[idx];
    const float4 x3 = r3[idx];
    a0 += w.x * x0.x + w.y * x0.y + w.z * x0.z + w.w * x0.w;
    a1 += w.x * x1.x + w.y * x1.y + w.z * x1.z + w.w * x1.w;
    a2 += w.x * x2.x + w.y * x2.y + w.z * x2.z + w.w * x2.w;
    a3 += w.x * x3.x + w.y * x3.y + w.z * x3.z + w.w * x3.w;
  }
#pragma unroll
  for (int m = 1; m <= 8; m <<= 1) {
    a0 += __shfl_xor(a0, m);
    a1 += __shfl_xor(a1, m);
    a2 += __shfl_xor(a2, m);
    a3 += __shfl_xor(a3, m);
  }
  if (l16 == 0) {
    const float bb = b1[j];
    h[(size_t)b0 * HID + j]       = fmaxf(a0 + bb, 0.f);
    h[(size_t)(b0 + 1) * HID + j] = fmaxf(a1 + bb, 0.f);
    h[(size_t)(b0 + 2) * HID + j] = fmaxf(a2 + bb, 0.f);
    h[(size_t)(b0 + 3) * HID + j] = fmaxf(a3 + bb, 0.f);
  }
}

// Layer 2: one wave per (4-k tile, 4-batch tile), 512-dot.
// Grid: 256 k-quads * 8 b-quads = 2048 one-wave blocks.
__global__ __launch_bounds__(64) void layer2_kernel(
    const float* __restrict__ h, const float* __restrict__ W2,
    const float* __restrict__ b2, float* __restrict__ out) {
  const int lane = threadIdx.x;
  const int g    = lane >> 4;
  const int l16  = lane & 15;
  const int kq   = blockIdx.x >> 3;        // 0..255
  const int b0   = (blockIdx.x & 7) << 2;
  const int k    = (kq << 2) + g;

  const float4* w4 = reinterpret_cast<const float4*>(W2 + (size_t)k * HID);
  const float4* h0 = reinterpret_cast<const float4*>(h + (size_t)b0 * HID);
  const float4* h1 = reinterpret_cast<const float4*>(h + (size_t)(b0 + 1) * HID);
  const float4* h2 = reinterpret_cast<const float4*>(h + (size_t)(b0 + 2) * HID);
  const float4* h3 = reinterpret_cast<const float4*>(h + (size_t)(b0 + 3) * HID);
  float a0 = 0.f, a1 = 0.f, a2 = 0.f, a3 = 0.f;
#pragma unroll
  for (int t = 0; t < 8; ++t) {            // 128 float4 / 16 lanes
    const int idx = l16 + 16 * t;
    const float4 w = w4[idx];
    const float4 x0 = h0[idx];
    const float4 x1 = h1[idx];
    const float4 x2 = h2[idx];
    const float4 x3 = h3[idx];
    a0 += w.x * x0.x + w.y * x0.y + w.z * x0.z + w.w * x0.w;
    a1 += w.x * x1.x + w.y * x1.y + w.z * x1.z + w.w * x1.w;
    a2 += w.x * x2.x + w.y * x2.y + w.z * x2.z + w.w * x2.w;
    a3 += w.x * x3.x + w.y * x3.y + w.z * x3.z + w.w * x3.w;
  }
#pragma unroll
  for (int m = 1; m <= 8; m <<= 1) {
    a0 += __shfl_xor(a0, m);
    a1 += __shfl_xor(a1, m);
    a2 += __shfl_xor(a2, m);
    a3 += __shfl_xor(a3, m);
  }
  if (l16 == 0) {
    const float bb = b2[k];
    out[(size_t)b0 * SS * OUTD + k]       = a0 + bb;
    out[(size_t)(b0 + 1) * SS * OUTD + k] = a1 + bb;
    out[(size_t)(b0 + 2) * SS * OUTD + k] = a2 + bb;
    out[(size_t)(b0 + 3) * SS * OUTD + k] = a3 + bb;
  }
}

// Broadcast (round-6 proven form): block = (b, s-chunk of 8 rows).
// Grid = 32*128 = 4096 blocks. Each thread reads one float4 of out[b,0,:]
// (L2/L3-hot) and stores it to 8 rows; contiguous 4 KB per row per block.
__global__ __launch_bounds__(256) void bcast_kernel(float* __restrict__ out) {
  const int b  = blockIdx.x >> 7;          // 0..31
  const int sc = blockIdx.x & 127;         // 0..127
  float4* __restrict__ base =
      reinterpret_cast<float4*>(out) + (size_t)b * SS * (OUTD / 4);
  const float4 v = base[threadIdx.x];      // source row s=0
  const int s0 = sc << 3;
#pragma unroll
  for (int i = 0; i < 8; ++i) {
    const int s = s0 + i;
    if (s != 0) base[(size_t)s * (OUTD / 4) + threadIdx.x] = v;
  }
}

extern "C" void kernel_launch(void* const* d_in, const int* in_sizes, int n_in,
                              void* d_out, int out_size, void* d_ws, size_t ws_size,
                              hipStream_t stream) {
  const float* rep = (const float*)d_in[0];
  // d_in[1] = size_matrix: only its shape matters (ones_like) -> unused
  const float* W1 = (const float*)d_in[2];
  const float* b1 = (const float*)d_in[3];
  const float* W2 = (const float*)d_in[4];
  const float* b2 = (const float*)d_in[5];
  float* out = (float*)d_out;
  float* h   = (float*)d_ws;               // 32*512 floats = 64 KB

  layer1_kernel<<<1024, 64, 0, stream>>>(rep, W1, b1, h);
  layer2_kernel<<<2048, 64, 0, stream>>>(h, W2, b2, out);
  bcast_kernel<<<BB * 128, 256, 0, stream>>>(out);
}